// Round 3
// baseline (946.773 us; speedup 1.0000x reference)
//
#include <hip/hip_runtime.h>

// ---------------- problem constants (fixed by setup_inputs) ----------------
#define NB   32
#define NLQ  300
#define ND   256
#define NH   8
#define NHD  32
#define NLV  8400          // 80*80 + 40*40 + 20*20
#define MVAL (NB * NLV)    // 268800 rows of value
#define MQ   (NB * NLQ)    // 9600 query rows
#define NCHUNK (MVAL / 128) // 2100 chunks of 128 rows for gemm_v

typedef unsigned short u16b;
typedef __bf16 bf16x8 __attribute__((ext_vector_type(8)));
typedef float  f32x4v __attribute__((ext_vector_type(4)));

__device__ __forceinline__ u16b f2b(float f) {          // fp32 -> bf16 RNE
  union { float f; unsigned u; } x; x.f = f;
  unsigned r = x.u + 0x7fffu + ((x.u >> 16) & 1u);
  return (u16b)(r >> 16);
}
__device__ __forceinline__ float b2f(u16b h) {
  union { float f; unsigned u; } x; x.u = ((unsigned)h) << 16;
  return x.f;
}
__device__ __forceinline__ unsigned pack2(float a, float b) {
  return (unsigned)f2b(a) | ((unsigned)f2b(b) << 16);
}
__device__ __forceinline__ float blo(unsigned u) {
  union { float f; unsigned v; } x; x.v = u << 16; return x.f;
}
__device__ __forceinline__ float bhi(unsigned u) {
  union { float f; unsigned v; } x; x.v = u & 0xffff0000u; return x.f;
}

// ---------------------------------------------------------------------------
// prep: transpose weights to [n][k] bf16. Wcat = [Woff | Wattn] with hi/lo
// split. grid 544 x 256
__global__ void prep_weights(const float* __restrict__ Wv, const float* __restrict__ Woff,
                             const float* __restrict__ Wattn, const float* __restrict__ Wout,
                             u16b* __restrict__ WvT, u16b* __restrict__ WcatH,
                             u16b* __restrict__ WcatL, u16b* __restrict__ WoutT) {
  const int n = blockIdx.x, k = threadIdx.x;
  if (n < 256) {
    WvT [n * 256 + k] = f2b(Wv  [k * 256 + n]);
    WoutT[n * 256 + k] = f2b(Wout[k * 256 + n]);
  } else {
    const int c = n - 256; // 0..287
    const float f = (c < 192) ? Woff[k * 192 + c] : Wattn[k * 96 + (c - 192)];
    const u16b hi = f2b(f);
    WcatH[c * 256 + k] = hi;
    WcatL[c * 256 + k] = f2b(f - b2f(hi));
  }
}

// ---------------------------------------------------------------------------
// STAGE 1: v = value @ Wv + bv -> bf16 [B][H][LV][32].
// B (WvT, 256x256 bf16) fully LDS-resident, padded row stride 264 u16b
// (528 B -> frag-read banks 2-way aliased only = free). NO barriers in the
// K loop: each wave owns 16 rows per 128-row chunk, streams A global->reg
// (frag-pattern loads are coalesced: 16 rows x 128 B fully-consumed segments),
// converts in-reg, 8 ksteps x 16 n-tiles of ds_read_b128 + MFMA.
// Persistent grid 256 blocks x 512 threads (1 block/CU by LDS, 8 waves).
__global__ __launch_bounds__(512, 2) void gemm_v(
    const float* __restrict__ A, const u16b* __restrict__ WvT,
    const float* __restrict__ bv, u16b* __restrict__ outb) {
  __shared__ u16b Bs[256 * 264];   // 135168 B

  const int t = threadIdx.x;
#pragma unroll
  for (int i = 0; i < 16; ++i) {
    const int c = i * 512 + t;          // 8192 uint4 chunks of WvT
    const int n = c >> 5, kg = c & 31;
    *(uint4*)&Bs[n * 264 + kg * 8] = *(const uint4*)&WvT[n * 256 + kg * 8];
  }
  __syncthreads();

  const int w = t >> 6, lane = t & 63;
  const int lr = lane & 15, kq = lane >> 4;

  float bias_r[16];
#pragma unroll
  for (int in = 0; in < 16; ++in) bias_r[in] = bv[in * 16 + lr];

  f32x4v acc[16];
  const f32x4v zero = {0.f, 0.f, 0.f, 0.f};
#pragma unroll
  for (int in = 0; in < 16; ++in) acc[in] = zero;

  float4 abuf[16];
  int c = blockIdx.x;
  {
    const float* ap = A + (size_t)(c * 128 + w * 16 + lr) * ND + kq * 8;
#pragma unroll
    for (int ks = 0; ks < 8; ++ks) {
      abuf[2 * ks]     = *(const float4*)(ap + ks * 32);
      abuf[2 * ks + 1] = *(const float4*)(ap + ks * 32 + 4);
    }
  }

  while (true) {
    union { uint4 u; bf16x8 v; } afrag[8];
#pragma unroll
    for (int ks = 0; ks < 8; ++ks) {
      const float4 u0 = abuf[2 * ks], u1 = abuf[2 * ks + 1];
      afrag[ks].u.x = pack2(u0.x, u0.y); afrag[ks].u.y = pack2(u0.z, u0.w);
      afrag[ks].u.z = pack2(u1.x, u1.y); afrag[ks].u.w = pack2(u1.z, u1.w);
    }
    const int cn = c + 256;
    const bool more = (cn < NCHUNK);
    if (more) {   // prefetch next chunk's A during compute
      const float* ap = A + (size_t)(cn * 128 + w * 16 + lr) * ND + kq * 8;
#pragma unroll
      for (int ks = 0; ks < 8; ++ks) {
        abuf[2 * ks]     = *(const float4*)(ap + ks * 32);
        abuf[2 * ks + 1] = *(const float4*)(ap + ks * 32 + 4);
      }
    }
#pragma unroll
    for (int ks = 0; ks < 8; ++ks) {
      const int kb = ks * 32 + kq * 8;
#pragma unroll
      for (int in = 0; in < 16; ++in) {
        const bf16x8 bf = *(const bf16x8*)&Bs[(in * 16 + lr) * 264 + kb];
        acc[in] = __builtin_amdgcn_mfma_f32_16x16x32_bf16(afrag[ks].v, bf, acc[in], 0, 0, 0);
      }
    }
    // epilogue: store chunk c, reset acc
    const int row0 = c * 128;
    const int b0 = row0 / NLV;
    const int rem0 = row0 - b0 * NLV;
    const int offw = w * 16 + kq * 4;
#pragma unroll
    for (int rg = 0; rg < 4; ++rg) {
      int pos = rem0 + offw + rg;
      int b = b0;
      if (pos >= NLV) { pos -= NLV; b++; }
#pragma unroll
      for (int in = 0; in < 16; ++in) {
        const int h = in >> 1, ch = (in & 1) * 16 + lr;
        outb[(((size_t)(b * NH + h)) * NLV + pos) * NHD + ch] = f2b(acc[in][rg] + bias_r[in]);
        acc[in][rg] = 0.f;
      }
    }
    if (!more) break;
    c = cn;
  }
}

// ---------------------------------------------------------------------------
// STAGE 2: query-head GEMM, N split into 3 slices of 96 (grid = 300*3).
// BM=32, BN=96, hi/lo 3-term bf16 split for fp32-grade accuracy. Fused
// epilogue: slices 0/1 emit sampling locations, slice 2 emits softmax attn.
__global__ __launch_bounds__(256, 4) void gemm_qh3(
    const float* __restrict__ A, const u16b* __restrict__ Bhi, const u16b* __restrict__ Blo,
    const float* __restrict__ boff, const float* __restrict__ battn,
    const float* __restrict__ refp, float* __restrict__ pb) {
  constexpr int STR = 40, RSTR = 97;
  __shared__ __align__(16) char smem[20480];
  u16b* Ah = (u16b*)smem;                 // 32*40*2 = 2560
  u16b* Al = (u16b*)(smem + 2560);        // 2560
  u16b* Bh = (u16b*)(smem + 5120);        // 96*40*2 = 7680
  u16b* Bl = (u16b*)(smem + 12800);       // 7680
  float* raw = (float*)(smem + 5120);     // overlay after K loop: 32*97*4 = 12416

  const int slice = blockIdx.x % 3;
  const int mch   = blockIdx.x / 3;
  const int N0 = slice * 96;
  const int row0 = mch * 32;

  const int t = threadIdx.x;
  const int wid = t >> 6, lane = t & 63;
  const int lr = lane & 15, kq = lane >> 4;
  const int wm = wid & 1, wn = wid >> 1;

  f32x4v acc[3];
  const f32x4v zero = {0.f, 0.f, 0.f, 0.f};
#pragma unroll
  for (int j = 0; j < 3; ++j) acc[j] = zero;

  for (int ks = 0; ks < 8; ++ks) {
    const int k0 = ks * 32;
    if (t < 128) {   // A: 32x32 fp32 -> hi/lo bf16
      const int fi = t * 8;
      const int r = fi >> 5, kk = fi & 31;
      const float* src = A + (size_t)(row0 + r) * ND + k0 + kk;
      const float4 u0 = *(const float4*)src;
      const float4 u1 = *(const float4*)(src + 4);
      const float vv[8] = {u0.x, u0.y, u0.z, u0.w, u1.x, u1.y, u1.z, u1.w};
      uint4 hw;
      hw.x = pack2(vv[0], vv[1]); hw.y = pack2(vv[2], vv[3]);
      hw.z = pack2(vv[4], vv[5]); hw.w = pack2(vv[6], vv[7]);
      *(uint4*)&Ah[r * STR + kk] = hw;
      float lo[8];
#pragma unroll
      for (int j = 0; j < 8; ++j) lo[j] = vv[j] - b2f(f2b(vv[j]));
      uint4 lw;
      lw.x = pack2(lo[0], lo[1]); lw.y = pack2(lo[2], lo[3]);
      lw.z = pack2(lo[4], lo[5]); lw.w = pack2(lo[6], lo[7]);
      *(uint4*)&Al[r * STR + kk] = lw;
    }
#pragma unroll
    for (int fi = t * 8; fi < 96 * 32; fi += 2048) {
      const int n = fi >> 5, kk = fi & 31;
      *(uint4*)&Bh[n * STR + kk] = *(const uint4*)&Bhi[(N0 + n) * ND + k0 + kk];
      *(uint4*)&Bl[n * STR + kk] = *(const uint4*)&Blo[(N0 + n) * ND + k0 + kk];
    }
    __syncthreads();
    const int rr = wm * 16 + lr;
    const bf16x8 af  = *(const bf16x8*)&Ah[rr * STR + kq * 8];
    const bf16x8 alf = *(const bf16x8*)&Al[rr * STR + kq * 8];
#pragma unroll
    for (int in = 0; in < 3; ++in) {
      const int nn = wn * 48 + in * 16 + lr;
      const bf16x8 bh = *(const bf16x8*)&Bh[nn * STR + kq * 8];
      const bf16x8 bl = *(const bf16x8*)&Bl[nn * STR + kq * 8];
      acc[in] = __builtin_amdgcn_mfma_f32_16x16x32_bf16(af,  bh, acc[in], 0, 0, 0);
      acc[in] = __builtin_amdgcn_mfma_f32_16x16x32_bf16(alf, bh, acc[in], 0, 0, 0);
      acc[in] = __builtin_amdgcn_mfma_f32_16x16x32_bf16(af,  bl, acc[in], 0, 0, 0);
    }
    __syncthreads();
  }
#pragma unroll
  for (int in = 0; in < 3; ++in) {
    const int dl = wn * 48 + in * 16 + lr;
    const int gd = N0 + dl;
    const float bias = (gd < 192) ? boff[gd] : battn[gd - 192];
#pragma unroll
    for (int rg = 0; rg < 4; ++rg) {
      const int row = wm * 16 + kq * 4 + rg;
      raw[row * RSTR + dl] = acc[in][rg] + bias;
    }
  }
  __syncthreads();
  const int q = t >> 3, gq = row0 + q;
  if (slice < 2) {
    const int j6 = t & 7;
    const float* rp = refp + (size_t)gq * 12;
    float* po = pb + (size_t)gq * 288;
#pragma unroll
    for (int e = 0; e < 6; ++e) {
      const int sl = j6 * 6 + e;           // 0..47 local sample idx
      const int si = slice * 48 + sl;      // global sample idx
      const int l = (si % 12) >> 2;
      const float ox = raw[q * RSTR + sl * 2 + 0];
      const float oy = raw[q * RSTR + sl * 2 + 1];
      po[si * 2 + 0] = rp[l * 4 + 0] + ox * rp[l * 4 + 2] * 0.5f;
      po[si * 2 + 1] = rp[l * 4 + 1] + oy * rp[l * 4 + 3] * 0.5f;
    }
  } else {
    const int h = t & 7;
    const float* r = raw + q * RSTR + h * 12;
    float lg[12], mx = -1e30f;
#pragma unroll
    for (int j = 0; j < 12; ++j) { lg[j] = r[j]; mx = fmaxf(mx, lg[j]); }
    float s = 0.f;
#pragma unroll
    for (int j = 0; j < 12; ++j) { lg[j] = __expf(lg[j] - mx); s += lg[j]; }
    const float inv = 1.f / s;
    float* po = pb + (size_t)gq * 288 + 192 + h * 12;
#pragma unroll
    for (int j = 0; j < 12; ++j) po[j] = lg[j] * inv;
  }
}

// ---------------------------------------------------------------------------
// STAGE 3: bilinear sample + attention-weighted sum. One wave per query,
// lane = h*8 + c4 (4 channels, uint2 loads), branch-free clamped loads with
// validity folded into weights. grid 2400 x 256.
__global__ __launch_bounds__(256) void msda_sample(
    const u16b* __restrict__ Vws, const float* __restrict__ pb,
    float* __restrict__ oattn) {
  const int gq0 = blockIdx.x * 4;
  const int t = threadIdx.x;
  __shared__ float spb[4 * 288];
  for (int i = t; i < 4 * 288; i += 256) spb[i] = pb[(size_t)gq0 * 288 + i];
  __syncthreads();
  const int wave = t >> 6, lane = t & 63;
  const int h = lane >> 3, c4 = lane & 7;
  const int gq = gq0 + wave;
  const int b = gq / NLQ;
  const float* P = spb + wave * 288;
  const u16b* vb = Vws + ((size_t)(b * NH + h) * NLV) * NHD + c4 * 4;
  const int WLS[3] = {80, 40, 20};
  const int S0S[3] = {0, 6400, 8000};
  float4 acc = {0.f, 0.f, 0.f, 0.f};
#pragma unroll
  for (int l = 0; l < 3; ++l) {
    const int Wl = WLS[l], s0 = S0S[l];
    const float Wf = (float)Wl;
#pragma unroll
    for (int p = 0; p < 4; ++p) {
      const int si = h * 12 + l * 4 + p;
      const float aw = P[192 + si];
      const float fx = P[si * 2 + 0] * Wf - 0.5f;
      const float fy = P[si * 2 + 1] * Wf - 0.5f;
      const float x0f = floorf(fx), y0f = floorf(fy);
      const float wx1 = fx - x0f, wx0 = 1.f - wx1;
      const float wy1 = fy - y0f, wy0 = 1.f - wy1;
      const int ix = (int)x0f, iy = (int)y0f;
      const float ax0 = ((unsigned)ix < (unsigned)Wl) ? wx0 : 0.f;
      const float ax1 = ((unsigned)(ix + 1) < (unsigned)Wl) ? wx1 : 0.f;
      const float ay0 = ((unsigned)iy < (unsigned)Wl) ? aw * wy0 : 0.f;
      const float ay1 = ((unsigned)(iy + 1) < (unsigned)Wl) ? aw * wy1 : 0.f;
      const int cx0 = min(max(ix, 0), Wl - 1);
      const int cx1 = min(max(ix + 1, 0), Wl - 1);
      const int cy0 = min(max(iy, 0), Wl - 1);
      const int cy1 = min(max(iy + 1, 0), Wl - 1);
      const int r0 = s0 + cy0 * Wl, r1 = s0 + cy1 * Wl;
      const uint2 u00 = *(const uint2*)(vb + (size_t)(r0 + cx0) * NHD);
      const uint2 u10 = *(const uint2*)(vb + (size_t)(r0 + cx1) * NHD);
      const uint2 u01 = *(const uint2*)(vb + (size_t)(r1 + cx0) * NHD);
      const uint2 u11 = *(const uint2*)(vb + (size_t)(r1 + cx1) * NHD);
      const float w00 = ay0 * ax0, w10 = ay0 * ax1;
      const float w01 = ay1 * ax0, w11 = ay1 * ax1;
      acc.x = fmaf(w00, blo(u00.x), acc.x); acc.y = fmaf(w00, bhi(u00.x), acc.y);
      acc.z = fmaf(w00, blo(u00.y), acc.z); acc.w = fmaf(w00, bhi(u00.y), acc.w);
      acc.x = fmaf(w10, blo(u10.x), acc.x); acc.y = fmaf(w10, bhi(u10.x), acc.y);
      acc.z = fmaf(w10, blo(u10.y), acc.z); acc.w = fmaf(w10, bhi(u10.y), acc.w);
      acc.x = fmaf(w01, blo(u01.x), acc.x); acc.y = fmaf(w01, bhi(u01.x), acc.y);
      acc.z = fmaf(w01, blo(u01.y), acc.z); acc.w = fmaf(w01, bhi(u01.y), acc.w);
      acc.x = fmaf(w11, blo(u11.x), acc.x); acc.y = fmaf(w11, bhi(u11.x), acc.y);
      acc.z = fmaf(w11, blo(u11.y), acc.z); acc.w = fmaf(w11, bhi(u11.y), acc.w);
    }
  }
  *(float4*)(oattn + (size_t)gq * ND + h * NHD + c4 * 4) = acc;
}

// ---------------------------------------------------------------------------
// STAGE 4: out = oattn @ Wout + bout. BM=32, N split in 2 slices of 128,
// grid 600, small LDS -> high occupancy.
__global__ __launch_bounds__(256, 4) void gemm_out(
    const float* __restrict__ A, const u16b* __restrict__ Bhi,
    const float* __restrict__ bias0, float* __restrict__ outf) {
  constexpr int STR = 40;
  __shared__ u16b Ah[32 * STR];
  __shared__ u16b Bh[128 * STR];

  const int slice = blockIdx.x & 1;
  const int mch   = blockIdx.x >> 1;
  const int N0 = slice * 128;
  const int row0 = mch * 32;

  const int t = threadIdx.x;
  const int wid = t >> 6, lane = t & 63;
  const int lr = lane & 15, kq = lane >> 4;
  const int wm = wid & 1, wn = wid >> 1;

  f32x4v acc[4];
  const f32x4v zero = {0.f, 0.f, 0.f, 0.f};
#pragma unroll
  for (int j = 0; j < 4; ++j) acc[j] = zero;

  for (int ks = 0; ks < 8; ++ks) {
    const int k0 = ks * 32;
    if (t < 128) {
      const int fi = t * 8;
      const int r = fi >> 5, kk = fi & 31;
      const float* src = A + (size_t)(row0 + r) * ND + k0 + kk;
      const float4 u0 = *(const float4*)src;
      const float4 u1 = *(const float4*)(src + 4);
      uint4 hw;
      hw.x = pack2(u0.x, u0.y); hw.y = pack2(u0.z, u0.w);
      hw.z = pack2(u1.x, u1.y); hw.w = pack2(u1.z, u1.w);
      *(uint4*)&Ah[r * STR + kk] = hw;
    }
#pragma unroll
    for (int fi = t * 8; fi < 128 * 32; fi += 2048) {
      const int n = fi >> 5, kk = fi & 31;
      *(uint4*)&Bh[n * STR + kk] = *(const uint4*)&Bhi[(N0 + n) * ND + k0 + kk];
    }
    __syncthreads();
    const int rr = wm * 16 + lr;
    const bf16x8 af = *(const bf16x8*)&Ah[rr * STR + kq * 8];
#pragma unroll
    for (int in = 0; in < 4; ++in) {
      const int nn = wn * 64 + in * 16 + lr;
      const bf16x8 bh = *(const bf16x8*)&Bh[nn * STR + kq * 8];
      acc[in] = __builtin_amdgcn_mfma_f32_16x16x32_bf16(af, bh, acc[in], 0, 0, 0);
    }
    __syncthreads();
  }
#pragma unroll
  for (int in = 0; in < 4; ++in) {
    const int d = N0 + wn * 64 + in * 16 + lr;
    const float bias = bias0[d];
#pragma unroll
    for (int rg = 0; rg < 4; ++rg) {
      const int gr = row0 + wm * 16 + kq * 4 + rg;
      outf[(size_t)gr * ND + d] = acc[in][rg] + bias;
    }
  }
}

// ---------------------------------------------------------------------------
extern "C" void kernel_launch(void* const* d_in, const int* in_sizes, int n_in,
                              void* d_out, int out_size, void* d_ws, size_t ws_size,
                              hipStream_t stream) {
  (void)in_sizes; (void)n_in; (void)out_size; (void)ws_size;
  const float* query = (const float*)d_in[0];
  const float* refp  = (const float*)d_in[1];
  const float* value = (const float*)d_in[2];
  const float* Wv    = (const float*)d_in[5];
  const float* bv    = (const float*)d_in[6];
  const float* Woff  = (const float*)d_in[7];
  const float* boff  = (const float*)d_in[8];
  const float* Wattn = (const float*)d_in[9];
  const float* battn = (const float*)d_in[10];
  const float* Wout  = (const float*)d_in[11];
  const float* bout  = (const float*)d_in[12];
  float* out = (float*)d_out;

  char* w = (char*)d_ws;
  u16b*  v_ws  = (u16b*)w;  w += (size_t)MVAL * ND * 2;
  u16b*  WvT   = (u16b*)w;  w += (size_t)256 * 256 * 2;
  u16b*  WoutT = (u16b*)w;  w += (size_t)256 * 256 * 2;
  u16b*  WcatH = (u16b*)w;  w += (size_t)288 * 256 * 2;
  u16b*  WcatL = (u16b*)w;  w += (size_t)288 * 256 * 2;
  float* pb    = (float*)w; w += (size_t)MQ * 288 * 4;
  float* oattn = (float*)w; w += (size_t)MQ * ND * 4;

  prep_weights<<<544, 256, 0, stream>>>(Wv, Woff, Wattn, Wout, WvT, WcatH, WcatL, WoutT);
  gemm_v<<<256, 512, 0, stream>>>(value, WvT, bv, v_ws);
  gemm_qh3<<<900, 256, 0, stream>>>(query, WcatH, WcatL, boff, battn, refp, pb);
  msda_sample<<<2400, 256, 0, stream>>>(v_ws, pb, oattn);
  gemm_out<<<600, 256, 0, stream>>>(oattn, WoutT, bout, out);
}

// Round 4
// 937.588 us; speedup vs baseline: 1.0098x; 1.0098x over previous
//
#include <hip/hip_runtime.h>

// ---------------- problem constants (fixed by setup_inputs) ----------------
#define NB   32
#define NLQ  300
#define ND   256
#define NH   8
#define NHD  32
#define NLV  8400          // 80*80 + 40*40 + 20*20
#define MVAL (NB * NLV)    // 268800 rows of value
#define MQ   (NB * NLQ)    // 9600 query rows
#define NCHUNK (MVAL / 128) // 2100 chunks of 128 rows for gemm_v

typedef unsigned short u16b;
typedef __bf16 bf16x8 __attribute__((ext_vector_type(8)));
typedef float  f32x4v __attribute__((ext_vector_type(4)));

__device__ __forceinline__ u16b f2b(float f) {          // fp32 -> bf16 RNE
  union { float f; unsigned u; } x; x.f = f;
  unsigned r = x.u + 0x7fffu + ((x.u >> 16) & 1u);
  return (u16b)(r >> 16);
}
__device__ __forceinline__ float b2f(u16b h) {
  union { float f; unsigned u; } x; x.u = ((unsigned)h) << 16;
  return x.f;
}
__device__ __forceinline__ unsigned pack2(float a, float b) {
  return (unsigned)f2b(a) | ((unsigned)f2b(b) << 16);
}
__device__ __forceinline__ float blo(unsigned u) {
  union { float f; unsigned v; } x; x.v = u << 16; return x.f;
}
__device__ __forceinline__ float bhi(unsigned u) {
  union { float f; unsigned v; } x; x.v = u & 0xffff0000u; return x.f;
}

// ---------------------------------------------------------------------------
// prep: transpose weights to [n][k] bf16. Wcat = [Woff | Wattn] with hi/lo
// split. grid 544 x 256
__global__ void prep_weights(const float* __restrict__ Wv, const float* __restrict__ Woff,
                             const float* __restrict__ Wattn, const float* __restrict__ Wout,
                             u16b* __restrict__ WvT, u16b* __restrict__ WcatH,
                             u16b* __restrict__ WcatL, u16b* __restrict__ WoutT) {
  const int n = blockIdx.x, k = threadIdx.x;
  if (n < 256) {
    WvT [n * 256 + k] = f2b(Wv  [k * 256 + n]);
    WoutT[n * 256 + k] = f2b(Wout[k * 256 + n]);
  } else {
    const int c = n - 256; // 0..287
    const float f = (c < 192) ? Woff[k * 192 + c] : Wattn[k * 96 + (c - 192)];
    const u16b hi = f2b(f);
    WcatH[c * 256 + k] = hi;
    WcatL[c * 256 + k] = f2b(f - b2f(hi));
  }
}

// ---------------------------------------------------------------------------
// STAGE 1: v = value @ Wv + bv -> bf16 [B][H][LV][32].
// B (WvT, 256x256 bf16) fully LDS-resident (stride 264 u16 -> frag reads are
// 2-way bank-aliased only = free). Barrier-free K loop: each wave owns 16 rows
// per 128-row chunk. QUARTER-K pipeline: abuf ring of 2 quarters (4 float4
// each = 32 VGPRs total) -> convert q, prefetch q+2, 32 MFMAs. Keeps live
// registers ~140 (round-3 version spilled: 1.45 GB scratch traffic).
// Persistent grid 256 blocks x 512 threads (1 block/CU by LDS, 8 waves).
__global__ __launch_bounds__(512, 2) void gemm_v(
    const float* __restrict__ A, const u16b* __restrict__ WvT,
    const float* __restrict__ bv, u16b* __restrict__ outb) {
  __shared__ u16b Bs[256 * 264];   // 135168 B

  const int t = threadIdx.x;
#pragma unroll
  for (int i = 0; i < 16; ++i) {
    const int c = i * 512 + t;          // 8192 uint4 chunks of WvT
    const int n = c >> 5, kg = c & 31;
    *(uint4*)&Bs[n * 264 + kg * 8] = *(const uint4*)&WvT[n * 256 + kg * 8];
  }
  __syncthreads();

  const int w = t >> 6, lane = t & 63;
  const int lr = lane & 15, kq = lane >> 4;

  float bias_r[16];
#pragma unroll
  for (int in = 0; in < 16; ++in) bias_r[in] = bv[in * 16 + lr];

  f32x4v acc[16];
  const f32x4v zero = {0.f, 0.f, 0.f, 0.f};
#pragma unroll
  for (int in = 0; in < 16; ++in) acc[in] = zero;

  // quarter q covers cols q*64 + kq*8 + {0..8} and +32.. (two 16x16x32 ksteps)
  float4 abuf[2][4];
#define LOADQ(dst, ap, q) do {                         \
    (dst)[0] = *(const float4*)((ap) + (q) * 64);      \
    (dst)[1] = *(const float4*)((ap) + (q) * 64 + 4);  \
    (dst)[2] = *(const float4*)((ap) + (q) * 64 + 32); \
    (dst)[3] = *(const float4*)((ap) + (q) * 64 + 36); \
  } while (0)

  int c = blockIdx.x;
  const float* ap = A + (size_t)(c * 128 + w * 16 + lr) * ND + kq * 8;
  LOADQ(abuf[0], ap, 0);
  LOADQ(abuf[1], ap, 1);

  while (true) {
    const int cn = c + 256;
    const bool more = (cn < NCHUNK);
    const float* apn = A + (size_t)(cn * 128 + w * 16 + lr) * ND + kq * 8;
#pragma unroll
    for (int q = 0; q < 4; ++q) {
      // convert current quarter -> two A fragments
      union { uint4 u; bf16x8 v; } af0, af1;
      {
        const float4 u0 = abuf[q & 1][0], u1 = abuf[q & 1][1];
        const float4 u2 = abuf[q & 1][2], u3 = abuf[q & 1][3];
        af0.u.x = pack2(u0.x, u0.y); af0.u.y = pack2(u0.z, u0.w);
        af0.u.z = pack2(u1.x, u1.y); af0.u.w = pack2(u1.z, u1.w);
        af1.u.x = pack2(u2.x, u2.y); af1.u.y = pack2(u2.z, u2.w);
        af1.u.z = pack2(u3.x, u3.y); af1.u.w = pack2(u3.z, u3.w);
      }
      // prefetch quarter q+2 (this chunk) or q-2 (next chunk)
      if (q < 2) {
        LOADQ(abuf[q & 1], ap, q + 2);
      } else if (more) {
        LOADQ(abuf[q & 1], apn, q - 2);
      }
      // 32 MFMAs against LDS-resident B
      const int cb0 = q * 64 + kq * 8;
#pragma unroll
      for (int in = 0; in < 16; ++in) {
        const bf16x8 b0 = *(const bf16x8*)&Bs[(in * 16 + lr) * 264 + cb0];
        acc[in] = __builtin_amdgcn_mfma_f32_16x16x32_bf16(af0.v, b0, acc[in], 0, 0, 0);
      }
#pragma unroll
      for (int in = 0; in < 16; ++in) {
        const bf16x8 b1 = *(const bf16x8*)&Bs[(in * 16 + lr) * 264 + cb0 + 32];
        acc[in] = __builtin_amdgcn_mfma_f32_16x16x32_bf16(af1.v, b1, acc[in], 0, 0, 0);
      }
    }
    // epilogue: store chunk c, reset acc.
    // C/D layout: row (in chunk) = w*16 + kq*4 + rg, col d = in*16 + lr.
    const int row0 = c * 128;
    const int b0 = row0 / NLV;
    const int rem0 = row0 - b0 * NLV;
    const int offw = w * 16 + kq * 4;
#pragma unroll
    for (int rg = 0; rg < 4; ++rg) {
      int pos = rem0 + offw + rg;
      int b = b0;
      if (pos >= NLV) { pos -= NLV; b++; }
#pragma unroll
      for (int in = 0; in < 16; ++in) {
        const int h = in >> 1, ch = (in & 1) * 16 + lr;
        outb[(((size_t)(b * NH + h)) * NLV + pos) * NHD + ch] = f2b(acc[in][rg] + bias_r[in]);
        acc[in][rg] = 0.f;
      }
    }
    if (!more) break;
    c = cn;
    ap = apn;
  }
#undef LOADQ
}

// ---------------------------------------------------------------------------
// STAGE 2: query-head GEMM, N split into 3 slices of 96 (grid = 300*3).
// BM=32, BN=96, hi/lo 3-term bf16 split for fp32-grade accuracy. Fused
// epilogue: slices 0/1 emit sampling locations, slice 2 emits softmax attn.
__global__ __launch_bounds__(256, 4) void gemm_qh3(
    const float* __restrict__ A, const u16b* __restrict__ Bhi, const u16b* __restrict__ Blo,
    const float* __restrict__ boff, const float* __restrict__ battn,
    const float* __restrict__ refp, float* __restrict__ pb) {
  constexpr int STR = 40, RSTR = 97;
  __shared__ __align__(16) char smem[20480];
  u16b* Ah = (u16b*)smem;                 // 32*40*2 = 2560
  u16b* Al = (u16b*)(smem + 2560);        // 2560
  u16b* Bh = (u16b*)(smem + 5120);        // 96*40*2 = 7680
  u16b* Bl = (u16b*)(smem + 12800);       // 7680
  float* raw = (float*)(smem + 5120);     // overlay after K loop: 32*97*4 = 12416

  const int slice = blockIdx.x % 3;
  const int mch   = blockIdx.x / 3;
  const int N0 = slice * 96;
  const int row0 = mch * 32;

  const int t = threadIdx.x;
  const int wid = t >> 6, lane = t & 63;
  const int lr = lane & 15, kq = lane >> 4;
  const int wm = wid & 1, wn = wid >> 1;

  f32x4v acc[3];
  const f32x4v zero = {0.f, 0.f, 0.f, 0.f};
#pragma unroll
  for (int j = 0; j < 3; ++j) acc[j] = zero;

  for (int ks = 0; ks < 8; ++ks) {
    const int k0 = ks * 32;
    if (t < 128) {   // A: 32x32 fp32 -> hi/lo bf16
      const int fi = t * 8;
      const int r = fi >> 5, kk = fi & 31;
      const float* src = A + (size_t)(row0 + r) * ND + k0 + kk;
      const float4 u0 = *(const float4*)src;
      const float4 u1 = *(const float4*)(src + 4);
      const float vv[8] = {u0.x, u0.y, u0.z, u0.w, u1.x, u1.y, u1.z, u1.w};
      uint4 hw;
      hw.x = pack2(vv[0], vv[1]); hw.y = pack2(vv[2], vv[3]);
      hw.z = pack2(vv[4], vv[5]); hw.w = pack2(vv[6], vv[7]);
      *(uint4*)&Ah[r * STR + kk] = hw;
      float lo[8];
#pragma unroll
      for (int j = 0; j < 8; ++j) lo[j] = vv[j] - b2f(f2b(vv[j]));
      uint4 lw;
      lw.x = pack2(lo[0], lo[1]); lw.y = pack2(lo[2], lo[3]);
      lw.z = pack2(lo[4], lo[5]); lw.w = pack2(lo[6], lo[7]);
      *(uint4*)&Al[r * STR + kk] = lw;
    }
#pragma unroll
    for (int fi = t * 8; fi < 96 * 32; fi += 2048) {
      const int n = fi >> 5, kk = fi & 31;
      *(uint4*)&Bh[n * STR + kk] = *(const uint4*)&Bhi[(N0 + n) * ND + k0 + kk];
      *(uint4*)&Bl[n * STR + kk] = *(const uint4*)&Blo[(N0 + n) * ND + k0 + kk];
    }
    __syncthreads();
    const int rr = wm * 16 + lr;
    const bf16x8 af  = *(const bf16x8*)&Ah[rr * STR + kq * 8];
    const bf16x8 alf = *(const bf16x8*)&Al[rr * STR + kq * 8];
#pragma unroll
    for (int in = 0; in < 3; ++in) {
      const int nn = wn * 48 + in * 16 + lr;
      const bf16x8 bh = *(const bf16x8*)&Bh[nn * STR + kq * 8];
      const bf16x8 bl = *(const bf16x8*)&Bl[nn * STR + kq * 8];
      acc[in] = __builtin_amdgcn_mfma_f32_16x16x32_bf16(af,  bh, acc[in], 0, 0, 0);
      acc[in] = __builtin_amdgcn_mfma_f32_16x16x32_bf16(alf, bh, acc[in], 0, 0, 0);
      acc[in] = __builtin_amdgcn_mfma_f32_16x16x32_bf16(af,  bl, acc[in], 0, 0, 0);
    }
    __syncthreads();
  }
#pragma unroll
  for (int in = 0; in < 3; ++in) {
    const int dl = wn * 48 + in * 16 + lr;
    const int gd = N0 + dl;
    const float bias = (gd < 192) ? boff[gd] : battn[gd - 192];
#pragma unroll
    for (int rg = 0; rg < 4; ++rg) {
      const int row = wm * 16 + kq * 4 + rg;
      raw[row * RSTR + dl] = acc[in][rg] + bias;
    }
  }
  __syncthreads();
  const int q = t >> 3, gq = row0 + q;
  if (slice < 2) {
    const int j6 = t & 7;
    const float* rp = refp + (size_t)gq * 12;
    float* po = pb + (size_t)gq * 288;
#pragma unroll
    for (int e = 0; e < 6; ++e) {
      const int sl = j6 * 6 + e;           // 0..47 local sample idx
      const int si = slice * 48 + sl;      // global sample idx
      const int l = (si % 12) >> 2;
      const float ox = raw[q * RSTR + sl * 2 + 0];
      const float oy = raw[q * RSTR + sl * 2 + 1];
      po[si * 2 + 0] = rp[l * 4 + 0] + ox * rp[l * 4 + 2] * 0.5f;
      po[si * 2 + 1] = rp[l * 4 + 1] + oy * rp[l * 4 + 3] * 0.5f;
    }
  } else {
    const int h = t & 7;
    const float* r = raw + q * RSTR + h * 12;
    float lg[12], mx = -1e30f;
#pragma unroll
    for (int j = 0; j < 12; ++j) { lg[j] = r[j]; mx = fmaxf(mx, lg[j]); }
    float s = 0.f;
#pragma unroll
    for (int j = 0; j < 12; ++j) { lg[j] = __expf(lg[j] - mx); s += lg[j]; }
    const float inv = 1.f / s;
    float* po = pb + (size_t)gq * 288 + 192 + h * 12;
#pragma unroll
    for (int j = 0; j < 12; ++j) po[j] = lg[j] * inv;
  }
}

// ---------------------------------------------------------------------------
// STAGE 3: bilinear sample + attention-weighted sum. One wave per query,
// lane = h*8 + c4 (4 channels, uint2 loads), branch-free clamped loads with
// validity folded into weights. grid 2400 x 256.
__global__ __launch_bounds__(256) void msda_sample(
    const u16b* __restrict__ Vws, const float* __restrict__ pb,
    float* __restrict__ oattn) {
  const int gq0 = blockIdx.x * 4;
  const int t = threadIdx.x;
  __shared__ float spb[4 * 288];
  for (int i = t; i < 4 * 288; i += 256) spb[i] = pb[(size_t)gq0 * 288 + i];
  __syncthreads();
  const int wave = t >> 6, lane = t & 63;
  const int h = lane >> 3, c4 = lane & 7;
  const int gq = gq0 + wave;
  const int b = gq / NLQ;
  const float* P = spb + wave * 288;
  const u16b* vb = Vws + ((size_t)(b * NH + h) * NLV) * NHD + c4 * 4;
  const int WLS[3] = {80, 40, 20};
  const int S0S[3] = {0, 6400, 8000};
  float4 acc = {0.f, 0.f, 0.f, 0.f};
#pragma unroll
  for (int l = 0; l < 3; ++l) {
    const int Wl = WLS[l], s0 = S0S[l];
    const float Wf = (float)Wl;
#pragma unroll
    for (int p = 0; p < 4; ++p) {
      const int si = h * 12 + l * 4 + p;
      const float aw = P[192 + si];
      const float fx = P[si * 2 + 0] * Wf - 0.5f;
      const float fy = P[si * 2 + 1] * Wf - 0.5f;
      const float x0f = floorf(fx), y0f = floorf(fy);
      const float wx1 = fx - x0f, wx0 = 1.f - wx1;
      const float wy1 = fy - y0f, wy0 = 1.f - wy1;
      const int ix = (int)x0f, iy = (int)y0f;
      const float ax0 = ((unsigned)ix < (unsigned)Wl) ? wx0 : 0.f;
      const float ax1 = ((unsigned)(ix + 1) < (unsigned)Wl) ? wx1 : 0.f;
      const float ay0 = ((unsigned)iy < (unsigned)Wl) ? aw * wy0 : 0.f;
      const float ay1 = ((unsigned)(iy + 1) < (unsigned)Wl) ? aw * wy1 : 0.f;
      const int cx0 = min(max(ix, 0), Wl - 1);
      const int cx1 = min(max(ix + 1, 0), Wl - 1);
      const int cy0 = min(max(iy, 0), Wl - 1);
      const int cy1 = min(max(iy + 1, 0), Wl - 1);
      const int r0 = s0 + cy0 * Wl, r1 = s0 + cy1 * Wl;
      const uint2 u00 = *(const uint2*)(vb + (size_t)(r0 + cx0) * NHD);
      const uint2 u10 = *(const uint2*)(vb + (size_t)(r0 + cx1) * NHD);
      const uint2 u01 = *(const uint2*)(vb + (size_t)(r1 + cx0) * NHD);
      const uint2 u11 = *(const uint2*)(vb + (size_t)(r1 + cx1) * NHD);
      const float w00 = ay0 * ax0, w10 = ay0 * ax1;
      const float w01 = ay1 * ax0, w11 = ay1 * ax1;
      acc.x = fmaf(w00, blo(u00.x), acc.x); acc.y = fmaf(w00, bhi(u00.x), acc.y);
      acc.z = fmaf(w00, blo(u00.y), acc.z); acc.w = fmaf(w00, bhi(u00.y), acc.w);
      acc.x = fmaf(w10, blo(u10.x), acc.x); acc.y = fmaf(w10, bhi(u10.x), acc.y);
      acc.z = fmaf(w10, blo(u10.y), acc.z); acc.w = fmaf(w10, bhi(u10.y), acc.w);
      acc.x = fmaf(w01, blo(u01.x), acc.x); acc.y = fmaf(w01, bhi(u01.x), acc.y);
      acc.z = fmaf(w01, blo(u01.y), acc.z); acc.w = fmaf(w01, bhi(u01.y), acc.w);
      acc.x = fmaf(w11, blo(u11.x), acc.x); acc.y = fmaf(w11, bhi(u11.x), acc.y);
      acc.z = fmaf(w11, blo(u11.y), acc.z); acc.w = fmaf(w11, bhi(u11.y), acc.w);
    }
  }
  *(float4*)(oattn + (size_t)gq * ND + h * NHD + c4 * 4) = acc;
}

// ---------------------------------------------------------------------------
// STAGE 4: out = oattn @ Wout + bout. BM=32, N split in 2 slices of 128,
// grid 600, small LDS -> high occupancy.
__global__ __launch_bounds__(256, 4) void gemm_out(
    const float* __restrict__ A, const u16b* __restrict__ Bhi,
    const float* __restrict__ bias0, float* __restrict__ outf) {
  constexpr int STR = 40;
  __shared__ u16b Ah[32 * STR];
  __shared__ u16b Bh[128 * STR];

  const int slice = blockIdx.x & 1;
  const int mch   = blockIdx.x >> 1;
  const int N0 = slice * 128;
  const int row0 = mch * 32;

  const int t = threadIdx.x;
  const int wid = t >> 6, lane = t & 63;
  const int lr = lane & 15, kq = lane >> 4;
  const int wm = wid & 1, wn = wid >> 1;

  f32x4v acc[4];
  const f32x4v zero = {0.f, 0.f, 0.f, 0.f};
#pragma unroll
  for (int j = 0; j < 4; ++j) acc[j] = zero;

  for (int ks = 0; ks < 8; ++ks) {
    const int k0 = ks * 32;
    if (t < 128) {
      const int fi = t * 8;
      const int r = fi >> 5, kk = fi & 31;
      const float* src = A + (size_t)(row0 + r) * ND + k0 + kk;
      const float4 u0 = *(const float4*)src;
      const float4 u1 = *(const float4*)(src + 4);
      uint4 hw;
      hw.x = pack2(u0.x, u0.y); hw.y = pack2(u0.z, u0.w);
      hw.z = pack2(u1.x, u1.y); hw.w = pack2(u1.z, u1.w);
      *(uint4*)&Ah[r * STR + kk] = hw;
    }
#pragma unroll
    for (int fi = t * 8; fi < 128 * 32; fi += 2048) {
      const int n = fi >> 5, kk = fi & 31;
      *(uint4*)&Bh[n * STR + kk] = *(const uint4*)&Bhi[(N0 + n) * ND + k0 + kk];
    }
    __syncthreads();
    const int rr = wm * 16 + lr;
    const bf16x8 af = *(const bf16x8*)&Ah[rr * STR + kq * 8];
#pragma unroll
    for (int in = 0; in < 4; ++in) {
      const int nn = wn * 64 + in * 16 + lr;
      const bf16x8 bh = *(const bf16x8*)&Bh[nn * STR + kq * 8];
      acc[in] = __builtin_amdgcn_mfma_f32_16x16x32_bf16(af, bh, acc[in], 0, 0, 0);
    }
    __syncthreads();
  }
#pragma unroll
  for (int in = 0; in < 4; ++in) {
    const int d = N0 + wn * 64 + in * 16 + lr;
    const float bias = bias0[d];
#pragma unroll
    for (int rg = 0; rg < 4; ++rg) {
      const int gr = row0 + wm * 16 + kq * 4 + rg;
      outf[(size_t)gr * ND + d] = acc[in][rg] + bias;
    }
  }
}

// ---------------------------------------------------------------------------
extern "C" void kernel_launch(void* const* d_in, const int* in_sizes, int n_in,
                              void* d_out, int out_size, void* d_ws, size_t ws_size,
                              hipStream_t stream) {
  (void)in_sizes; (void)n_in; (void)out_size; (void)ws_size;
  const float* query = (const float*)d_in[0];
  const float* refp  = (const float*)d_in[1];
  const float* value = (const float*)d_in[2];
  const float* Wv    = (const float*)d_in[5];
  const float* bv    = (const float*)d_in[6];
  const float* Woff  = (const float*)d_in[7];
  const float* boff  = (const float*)d_in[8];
  const float* Wattn = (const float*)d_in[9];
  const float* battn = (const float*)d_in[10];
  const float* Wout  = (const float*)d_in[11];
  const float* bout  = (const float*)d_in[12];
  float* out = (float*)d_out;

  char* w = (char*)d_ws;
  u16b*  v_ws  = (u16b*)w;  w += (size_t)MVAL * ND * 2;
  u16b*  WvT   = (u16b*)w;  w += (size_t)256 * 256 * 2;
  u16b*  WoutT = (u16b*)w;  w += (size_t)256 * 256 * 2;
  u16b*  WcatH = (u16b*)w;  w += (size_t)288 * 256 * 2;
  u16b*  WcatL = (u16b*)w;  w += (size_t)288 * 256 * 2;
  float* pb    = (float*)w; w += (size_t)MQ * 288 * 4;
  float* oattn = (float*)w; w += (size_t)MQ * ND * 4;

  prep_weights<<<544, 256, 0, stream>>>(Wv, Woff, Wattn, Wout, WvT, WcatH, WcatL, WoutT);
  gemm_v<<<256, 512, 0, stream>>>(value, WvT, bv, v_ws);
  gemm_qh3<<<900, 256, 0, stream>>>(query, WcatH, WcatL, boff, battn, refp, pb);
  msda_sample<<<2400, 256, 0, stream>>>(v_ws, pb, oattn);
  gemm_out<<<600, 256, 0, stream>>>(oattn, WoutT, bout, out);
}